// Round 3
// baseline (155.580 us; speedup 1.0000x reference)
//
#include <hip/hip_runtime.h>
#include <math.h>

// Problem constants: B=32, E=1024, H=1024, N=128, L=64, K=8
#define NB 32
#define NE 1024
#define NH 1024
#define NN 128
#define NL 64
#define NK 8
#define GS 8   // g-chunks for qk partial sums

__device__ __forceinline__ float dot4f(float4 a, float4 b) {
    return a.x * b.x + a.y * b.y + a.z * b.z + a.w * b.w;
}

// ---------------------------------------------------------------------------
// rowdot8: one wave computes dot(W[o,:], A[b,:]) + bias[o] for 8 consecutive b
// ---------------------------------------------------------------------------
template <int D>
__device__ void rowdot8(const float* __restrict__ A, const float* __restrict__ W,
                        const float* __restrict__ bias, float* __restrict__ C,
                        int wid) {
    int lane = threadIdx.x & 63;
    int o  = wid >> 2;          // 0..1023
    int b0 = (wid & 3) * 8;     // batch group of 8
    const float4* Wr = (const float4*)(W + (size_t)o * D);
    const float4* Ar[8];
#pragma unroll
    for (int i = 0; i < 8; ++i) Ar[i] = (const float4*)(A + (size_t)(b0 + i) * D);
    float acc[8] = {0.f, 0.f, 0.f, 0.f, 0.f, 0.f, 0.f, 0.f};
#pragma unroll
    for (int c = 0; c < D / 256; ++c) {
        float4 w4 = Wr[c * 64 + lane];
#pragma unroll
        for (int i = 0; i < 8; ++i) {
            float4 a = Ar[i][c * 64 + lane];
            acc[i] += dot4f(w4, a);
        }
    }
#pragma unroll
    for (int s = 32; s; s >>= 1)
#pragma unroll
        for (int i = 0; i < 8; ++i) acc[i] += __shfl_down(acc[i], s, 64);
    if (lane == 0) {
        float bb = bias[o];
#pragma unroll
        for (int i = 0; i < 8; ++i) C[(size_t)(b0 + i) * NH + o] = acc[i] + bb;
    }
}

// ---------------------------------------------------------------------------
// FAT1: blocks [0,1024): scores[b,n] = cache_keys[b,n,:]·inputs[b,:]
//       blocks [1024,2048): query = inputs @ Wq^T + bq
//       block 0 also zeroes the per-batch completion counters.
// ---------------------------------------------------------------------------
__global__ void fat1_kernel(const float* __restrict__ cache_keys,
                            const float* __restrict__ inputs,
                            const float* __restrict__ Wq,
                            const float* __restrict__ bq,
                            float* __restrict__ scores,
                            float* __restrict__ query,
                            int* __restrict__ cnt) {
    if (blockIdx.x == 0 && threadIdx.x < NB) cnt[threadIdx.x] = 0;
    if (blockIdx.x < 1024) {
        int wid  = blockIdx.x * 4 + (threadIdx.x >> 6);   // 0..4095
        int lane = threadIdx.x & 63;
        int b = wid >> 7, n = wid & 127;
        const float4* ck = (const float4*)(cache_keys + ((size_t)b * NN + n) * NE);
        const float4* in = (const float4*)(inputs + (size_t)b * NE);
        float acc = 0.f;
#pragma unroll
        for (int c = 0; c < 4; ++c) acc += dot4f(ck[c * 64 + lane], in[c * 64 + lane]);
#pragma unroll
        for (int s = 32; s; s >>= 1) acc += __shfl_down(acc, s, 64);
        if (lane == 0) scores[b * NN + n] = acc;
    } else {
        int wid = (blockIdx.x - 1024) * 4 + (threadIdx.x >> 6);  // 0..4095
        rowdot8<1024>(inputs, Wq, bq, query, wid);
    }
}

// ---------------------------------------------------------------------------
// FAT2: blocks [0,1024): pqk partial GEMM, tiled so each block reads only
//       16KB of Wk: block = (gs in 8) x (hs in 32) x (bg in 4).
//       blocks [1024,1056): per-batch top-8 + softmax -> tidx, weights.
// pqk[gs][b][h] = sum_{g in gs-chunk of 128} query[b,g] * Wk[g,h]
// (bk dropped: q·bk is constant over l -> cancels in the l-softmax)
// ---------------------------------------------------------------------------
__global__ void fat2_kernel(const float* __restrict__ query,
                            const float* __restrict__ Wk,
                            const float* __restrict__ scores,
                            float* __restrict__ pqk,
                            int* __restrict__ top_idx,
                            float* __restrict__ weights) {
    __shared__ float qlds[128 * 8];     // [g_local][bj]  4KB
    __shared__ float red[8 * 32 * 8];   // [g_lane][h_local][bj] 8KB
    __shared__ float tv[NK];
    int t = threadIdx.x;
    if (blockIdx.x < 1024) {
        int gs = blockIdx.x & 7;
        int hs = (blockIdx.x >> 3) & 31;
        int bg = blockIdx.x >> 8;
        int b0 = bg * 8;
        // stage q chunk: [g 128][bj 8] (transpose of query layout; 4KB, cheap)
#pragma unroll
        for (int j = 0; j < 4; ++j) {
            int idx = t * 4 + j;
            int g = idx >> 3, bj = idx & 7;
            qlds[idx] = query[(size_t)(b0 + bj) * NH + gs * 128 + g];
        }
        __syncthreads();
        int h_local = t & 31, g_lane = t >> 5;
        int h = hs * 32 + h_local;
        float acc[8] = {0.f, 0.f, 0.f, 0.f, 0.f, 0.f, 0.f, 0.f};
#pragma unroll
        for (int i = 0; i < 16; ++i) {
            int g_local = g_lane * 16 + i;
            float w = Wk[(size_t)(gs * 128 + g_local) * NH + h];
            float4 q0 = *(const float4*)&qlds[g_local * 8];
            float4 q1 = *(const float4*)&qlds[g_local * 8 + 4];
            acc[0] += q0.x * w; acc[1] += q0.y * w; acc[2] += q0.z * w; acc[3] += q0.w * w;
            acc[4] += q1.x * w; acc[5] += q1.y * w; acc[6] += q1.z * w; acc[7] += q1.w * w;
        }
        *(float4*)&red[(g_lane * 32 + h_local) * 8]     = *(float4*)&acc[0];
        *(float4*)&red[(g_lane * 32 + h_local) * 8 + 4] = *(float4*)&acc[4];
        __syncthreads();
        int bj = t >> 5, hl = t & 31;
        float ssum = 0.f;
#pragma unroll
        for (int gl = 0; gl < 8; ++gl) ssum += red[(gl * 32 + hl) * 8 + bj];
        pqk[((size_t)gs * NB + b0 + bj) * NH + hs * 32 + hl] = ssum;
    } else {
        int b = blockIdx.x - 1024;
        if (t < 64) {
            float s0 = scores[b * NN + t];
            float s1 = scores[b * NN + 64 + t];
            for (int i = 0; i < NK; ++i) {
                float v = s0; int idx = t;
                if (s1 > v) { v = s1; idx = t + 64; }
#pragma unroll
                for (int s = 1; s < 64; s <<= 1) {
                    float ov = __shfl_xor(v, s, 64);
                    int   oi = __shfl_xor(idx, s, 64);
                    if (ov > v || (ov == v && oi < idx)) { v = ov; idx = oi; }
                }
                if (t == 0) { tv[i] = v; top_idx[b * NK + i] = idx; }
                if (idx == t)      s0 = -INFINITY;
                if (idx == t + 64) s1 = -INFINITY;
            }
        }
        __syncthreads();
        if (t < NK) {
            float e = __expf(tv[t] - tv[0]);   // tv[0] is the max
            float sum = e;
            sum += __shfl_xor(sum, 1, 64);
            sum += __shfl_xor(sum, 2, 64);
            sum += __shfl_xor(sum, 4, 64);
            weights[b * NK + t] = e / sum;
        }
    }
}

// ---------------------------------------------------------------------------
// ATTN: per (b,k) block, 1024 threads (16 waves), SINGLE pass over zones with
// per-wave online softmax (each wave owns 4 rows, no sync in stream loop),
// then a 4-stage pairwise wave merge in LDS. Last block per b assembles F.
// ---------------------------------------------------------------------------
__global__ __launch_bounds__(1024)
void attn_kernel(const float* __restrict__ pqk,
                 const float* __restrict__ cache_values,
                 const int* __restrict__ top_idx,
                 const float* __restrict__ weights,
                 const float* __restrict__ inputs,
                 float* __restrict__ patt,
                 float* __restrict__ F,
                 int* __restrict__ cnt) {
    int b = blockIdx.x >> 3, k = blockIdx.x & 7;
    __shared__ float qk_lds[NH];        // 4KB
    __shared__ float mbuf[8][NH];       // 32KB merge buffers
    __shared__ float md_lds[16][2];
    __shared__ int last_lds;
    int t = threadIdx.x;

    // qk[b,h] = sum_gs pqk[gs][b][h]   (all 1024 threads, coalesced)
    {
        float s = 0.f;
#pragma unroll
        for (int gs = 0; gs < GS; ++gs) s += pqk[((size_t)gs * NB + b) * NH + t];
        qk_lds[t] = s;
    }
    __syncthreads();

    int lane = t & 63, wv = t >> 6;
    float4 qk[4];
#pragma unroll
    for (int c = 0; c < 4; ++c) qk[c] = ((const float4*)qk_lds)[c * 64 + lane];

    int zi = top_idx[b * NK + k];
    const float* zbase = cache_values + (((size_t)b * NN + zi) * NL) * NH;

    float m = -INFINITY, d = 0.f;
    float4 acc[4];
#pragma unroll
    for (int c = 0; c < 4; ++c) acc[c] = make_float4(0.f, 0.f, 0.f, 0.f);

    // stream 4 rows per wave, online softmax (rows independent across waves)
#pragma unroll
    for (int r = 0; r < 4; ++r) {
        int l = wv * 4 + r;
        const float4* zr = (const float4*)(zbase + (size_t)l * NH);
        float4 z[4];
#pragma unroll
        for (int c = 0; c < 4; ++c) z[c] = zr[c * 64 + lane];
        float dot = 0.f;
#pragma unroll
        for (int c = 0; c < 4; ++c) dot += dot4f(z[c], qk[c]);
#pragma unroll
        for (int s = 1; s < 64; s <<= 1) dot += __shfl_xor(dot, s, 64);
        dot *= 0.03125f;                 // 1/sqrt(1024)
        float nm = fmaxf(m, dot);
        float scale = __expf(m - nm);    // first iter: exp(-inf)=0
        float p = __expf(dot - nm);
        d = d * scale + p;
#pragma unroll
        for (int c = 0; c < 4; ++c) {
            acc[c].x = acc[c].x * scale + p * z[c].x;
            acc[c].y = acc[c].y * scale + p * z[c].y;
            acc[c].z = acc[c].z * scale + p * z[c].z;
            acc[c].w = acc[c].w * scale + p * z[c].w;
        }
        m = nm;
    }

    // pairwise merge: 16 -> 8 -> 4 -> 2 -> 1 (upper half dumps, lower merges)
#pragma unroll
    for (int half = 8; half >= 1; half >>= 1) {
        if (wv >= half && wv < 2 * half) {
#pragma unroll
            for (int c = 0; c < 4; ++c) ((float4*)mbuf[wv - half])[c * 64 + lane] = acc[c];
            if (lane == 0) { md_lds[wv][0] = m; md_lds[wv][1] = d; }
        }
        __syncthreads();
        if (wv < half) {
            float mb = md_lds[wv + half][0], db = md_lds[wv + half][1];
            float nm = fmaxf(m, mb);
            float fa = __expf(m - nm), fb = __expf(mb - nm);
#pragma unroll
            for (int c = 0; c < 4; ++c) {
                float4 bv = ((const float4*)mbuf[wv])[c * 64 + lane];
                acc[c].x = acc[c].x * fa + bv.x * fb;
                acc[c].y = acc[c].y * fa + bv.y * fb;
                acc[c].z = acc[c].z * fa + bv.z * fb;
                acc[c].w = acc[c].w * fa + bv.w * fb;
            }
            d = d * fa + db * fb;
            m = nm;
        }
        __syncthreads();
    }

    // wave 0 holds the full H-wide result
    if (wv == 0) {
        float r_ = weights[b * NK + k] / d;
        float* pout = patt + ((size_t)b * NK + k) * NH;
#pragma unroll
        for (int c = 0; c < 4; ++c) {
            float4 o = acc[c];
            o.x *= r_; o.y *= r_; o.z *= r_; o.w *= r_;
            ((float4*)pout)[c * 64 + lane] = o;
        }
    }

    // F assembly by the last-arriving block for this b (device-scope release/acquire)
    __threadfence();
    __syncthreads();
    if (t == 0)
        last_lds = __hip_atomic_fetch_add(&cnt[b], 1, __ATOMIC_ACQ_REL,
                                          __HIP_MEMORY_SCOPE_AGENT);
    __syncthreads();
    if (last_lds == NK - 1) {
        __threadfence();   // acquire: other blocks' patt writes now visible
        float fsum = 0.f;
#pragma unroll
        for (int kk = 0; kk < NK; ++kk) fsum += patt[((size_t)b * NK + kk) * NH + t];
        F[(size_t)b * 2048 + t] = fsum;
        F[(size_t)b * 2048 + NH + t] = inputs[(size_t)b * NE + t];
    }
}

// ---------------------------------------------------------------------------
// FINAL: out = F @ Wc^T + bc
// ---------------------------------------------------------------------------
__global__ void final_kernel(const float* __restrict__ F,
                             const float* __restrict__ Wc,
                             const float* __restrict__ bc,
                             float* __restrict__ out) {
    int wid = blockIdx.x * 4 + (threadIdx.x >> 6);  // 0..4095
    rowdot8<2048>(F, Wc, bc, out, wid);
}

// ---------------------------------------------------------------------------
extern "C" void kernel_launch(void* const* d_in, const int* in_sizes, int n_in,
                              void* d_out, int out_size, void* d_ws, size_t ws_size,
                              hipStream_t stream) {
    const float* inputs       = (const float*)d_in[0];
    const float* Wq           = (const float*)d_in[1];
    const float* bq           = (const float*)d_in[2];
    const float* Wk           = (const float*)d_in[3];
    // d_in[4] = bk: cancels in the l-softmax (constant over l)
    const float* Wc           = (const float*)d_in[5];
    const float* bc           = (const float*)d_in[6];
    const float* cache_keys   = (const float*)d_in[7];
    const float* cache_values = (const float*)d_in[8];
    float* out = (float*)d_out;

    float* ws      = (float*)d_ws;
    float* scores  = ws;                       // 4096
    float* query   = scores + 4096;            // 32768
    float* pqk     = query + 32768;            // 8*32*1024 = 262144
    float* patt    = pqk + 262144;             // 32*8*1024 = 262144
    float* F       = patt + 262144;            // 65536
    float* weights = F + 65536;                // 256
    int*   tidx    = (int*)(weights + 256);    // 256 ints
    int*   cnt     = tidx + 256;               // 32 ints
    (void)ws_size; (void)n_in; (void)in_sizes; (void)out_size;

    fat1_kernel<<<2048, 256, 0, stream>>>(cache_keys, inputs, Wq, bq, scores, query, cnt);
    fat2_kernel<<<1056, 256, 0, stream>>>(query, Wk, scores, pqk, tidx, weights);
    attn_kernel<<<NB * NK, 1024, 0, stream>>>(pqk, cache_values, tidx, weights,
                                              inputs, patt, F, cnt);
    final_kernel<<<1024, 256, 0, stream>>>(F, Wc, bc, out);
}

// Round 4
// 67.282 us; speedup vs baseline: 2.3124x; 2.3124x over previous
//
#include <hip/hip_runtime.h>
#include <math.h>

// Problem constants: B=32, E=1024, H=1024, N=128, L=64, K=8
#define NB 32
#define NE 1024
#define NH 1024
#define NN 128
#define NL 64
#define NK 8
#define GS 8   // g-chunks for qk partial sums

__device__ __forceinline__ float dot4f(float4 a, float4 b) {
    return a.x * b.x + a.y * b.y + a.z * b.z + a.w * b.w;
}

// ---------------------------------------------------------------------------
// rowdot8: one wave computes dot(W[o,:], A[b,:]) + bias[o] for 8 consecutive b
// (D/256 c-iterations per wave; ~350 instructions total -> cheap)
// ---------------------------------------------------------------------------
template <int D>
__device__ void rowdot8(const float* __restrict__ A, const float* __restrict__ W,
                        const float* __restrict__ bias, float* __restrict__ C,
                        int wid) {
    int lane = threadIdx.x & 63;
    int o  = wid >> 2;          // 0..1023
    int b0 = (wid & 3) * 8;     // batch group of 8
    const float4* Wr = (const float4*)(W + (size_t)o * D);
    const float4* Ar[8];
#pragma unroll
    for (int i = 0; i < 8; ++i) Ar[i] = (const float4*)(A + (size_t)(b0 + i) * D);
    float acc[8] = {0.f, 0.f, 0.f, 0.f, 0.f, 0.f, 0.f, 0.f};
#pragma unroll
    for (int c = 0; c < D / 256; ++c) {
        float4 w4 = Wr[c * 64 + lane];
#pragma unroll
        for (int i = 0; i < 8; ++i) {
            float4 a = Ar[i][c * 64 + lane];
            acc[i] += dot4f(w4, a);
        }
    }
#pragma unroll
    for (int s = 32; s; s >>= 1)
#pragma unroll
        for (int i = 0; i < 8; ++i) acc[i] += __shfl_down(acc[i], s, 64);
    if (lane == 0) {
        float bb = bias[o];
#pragma unroll
        for (int i = 0; i < 8; ++i) C[(size_t)(b0 + i) * NH + o] = acc[i] + bb;
    }
}

// ---------------------------------------------------------------------------
// FAT1: blocks [0,1024): scores[b,n] = cache_keys[b,n,:]·inputs[b,:]
//       blocks [1024,2048): query = inputs @ Wq^T + bq
// ---------------------------------------------------------------------------
__global__ __launch_bounds__(256)
void fat1_kernel(const float* __restrict__ cache_keys,
                 const float* __restrict__ inputs,
                 const float* __restrict__ Wq,
                 const float* __restrict__ bq,
                 float* __restrict__ scores,
                 float* __restrict__ query) {
    if (blockIdx.x < 1024) {
        int wid  = blockIdx.x * 4 + (threadIdx.x >> 6);   // 0..4095
        int lane = threadIdx.x & 63;
        int b = wid >> 7, n = wid & 127;
        const float4* ck = (const float4*)(cache_keys + ((size_t)b * NN + n) * NE);
        const float4* in = (const float4*)(inputs + (size_t)b * NE);
        float acc = 0.f;
#pragma unroll
        for (int c = 0; c < 4; ++c) acc += dot4f(ck[c * 64 + lane], in[c * 64 + lane]);
#pragma unroll
        for (int s = 32; s; s >>= 1) acc += __shfl_down(acc, s, 64);
        if (lane == 0) scores[b * NN + n] = acc;
    } else {
        int wid = (blockIdx.x - 1024) * 4 + (threadIdx.x >> 6);  // 0..4095
        rowdot8<1024>(inputs, Wq, bq, query, wid);
    }
}

// ---------------------------------------------------------------------------
// FAT2: blocks [0,1024): pqk partial GEMM, tiled so each block reads only
//       16KB of Wk: block = (gs in 8) x (hs in 32) x (bg in 4).
//       blocks [1024,1056): per-batch top-8 + softmax -> tidx, weights.
// pqk[gs][b][h] = sum_{g in gs-chunk of 128} query[b,g] * Wk[g,h]
// (bk dropped: q·bk is constant over l -> cancels in the l-softmax)
// ---------------------------------------------------------------------------
__global__ __launch_bounds__(256)
void fat2_kernel(const float* __restrict__ query,
                 const float* __restrict__ Wk,
                 const float* __restrict__ scores,
                 float* __restrict__ pqk,
                 int* __restrict__ top_idx,
                 float* __restrict__ weights) {
    __shared__ float qlds[128 * 8];     // [g_local][bj]  4KB
    __shared__ float red[8 * 32 * 8];   // [g_lane][h_local][bj] 8KB
    __shared__ float tv[NK];
    int t = threadIdx.x;
    if (blockIdx.x < 1024) {
        int gs = blockIdx.x & 7;
        int hs = (blockIdx.x >> 3) & 31;
        int bg = blockIdx.x >> 8;
        int b0 = bg * 8;
#pragma unroll
        for (int j = 0; j < 4; ++j) {
            int idx = t * 4 + j;
            int g = idx >> 3, bj = idx & 7;
            qlds[idx] = query[(size_t)(b0 + bj) * NH + gs * 128 + g];
        }
        __syncthreads();
        int h_local = t & 31, g_lane = t >> 5;
        int h = hs * 32 + h_local;
        float acc[8] = {0.f, 0.f, 0.f, 0.f, 0.f, 0.f, 0.f, 0.f};
#pragma unroll
        for (int i = 0; i < 16; ++i) {
            int g_local = g_lane * 16 + i;
            float w = Wk[(size_t)(gs * 128 + g_local) * NH + h];
            float4 q0 = *(const float4*)&qlds[g_local * 8];
            float4 q1 = *(const float4*)&qlds[g_local * 8 + 4];
            acc[0] += q0.x * w; acc[1] += q0.y * w; acc[2] += q0.z * w; acc[3] += q0.w * w;
            acc[4] += q1.x * w; acc[5] += q1.y * w; acc[6] += q1.z * w; acc[7] += q1.w * w;
        }
        *(float4*)&red[(g_lane * 32 + h_local) * 8]     = *(float4*)&acc[0];
        *(float4*)&red[(g_lane * 32 + h_local) * 8 + 4] = *(float4*)&acc[4];
        __syncthreads();
        int bj = t >> 5, hl = t & 31;
        float ssum = 0.f;
#pragma unroll
        for (int gl = 0; gl < 8; ++gl) ssum += red[(gl * 32 + hl) * 8 + bj];
        pqk[((size_t)gs * NB + b0 + bj) * NH + hs * 32 + hl] = ssum;
    } else {
        int b = blockIdx.x - 1024;
        if (t < 64) {
            float s0 = scores[b * NN + t];
            float s1 = scores[b * NN + 64 + t];
            for (int i = 0; i < NK; ++i) {
                float v = s0; int idx = t;
                if (s1 > v) { v = s1; idx = t + 64; }
#pragma unroll
                for (int s = 1; s < 64; s <<= 1) {
                    float ov = __shfl_xor(v, s, 64);
                    int   oi = __shfl_xor(idx, s, 64);
                    if (ov > v || (ov == v && oi < idx)) { v = ov; idx = oi; }
                }
                if (t == 0) { tv[i] = v; top_idx[b * NK + i] = idx; }
                if (idx == t)      s0 = -INFINITY;
                if (idx == t + 64) s1 = -INFINITY;
            }
        }
        __syncthreads();
        if (t < NK) {
            float e = __expf(tv[t] - tv[0]);   // tv[0] is the max
            float sum = e;
            sum += __shfl_xor(sum, 1, 64);
            sum += __shfl_xor(sum, 2, 64);
            sum += __shfl_xor(sum, 4, 64);
            weights[b * NK + t] = e / sum;
        }
    }
}

// ---------------------------------------------------------------------------
// ATTN: one 256-thread block per (b,k). Two passes over the zone:
//  phase1: 4 waves x 16 rows -> logits (HBM read, 256KB)
//  phase2: softmax (wave 0, retrieval weight folded in) then per-thread
//          float4 accumulate over the 64 rows (L2/L3-hot re-read).
// Low VGPR, ~4.6KB LDS -> 8 blocks/CU.
// ---------------------------------------------------------------------------
__global__ __launch_bounds__(256)
void attn_kernel(const float* __restrict__ pqk,
                 const float* __restrict__ cache_values,
                 const int* __restrict__ top_idx,
                 const float* __restrict__ weights,
                 float* __restrict__ patt) {
    int b = blockIdx.x >> 3, k = blockIdx.x & 7;
    __shared__ float qk_lds[NH];    // 4KB
    __shared__ float logits[NL];
    __shared__ float coef[NL];
    int t = threadIdx.x;

    // qk[b,h] = sum_gs pqk[gs][b][h]  (256 threads x float4, coalesced)
    {
        float4 s = make_float4(0.f, 0.f, 0.f, 0.f);
#pragma unroll
        for (int gs = 0; gs < GS; ++gs) {
            float4 p = ((const float4*)pqk)[((size_t)gs * NB + b) * 256 + t];
            s.x += p.x; s.y += p.y; s.z += p.z; s.w += p.w;
        }
        ((float4*)qk_lds)[t] = s;
    }
    __syncthreads();

    int lane = t & 63, wv = t >> 6;
    int zi = top_idx[b * NK + k];
    const float* zbase = cache_values + (((size_t)b * NN + zi) * NL) * NH;

    // phase 1: wave wv owns rows [wv*16, wv*16+16) -> logits
    {
        float4 qk[4];
#pragma unroll
        for (int c = 0; c < 4; ++c) qk[c] = ((const float4*)qk_lds)[c * 64 + lane];
        for (int r = 0; r < 16; ++r) {
            int l = wv * 16 + r;
            const float4* zr = (const float4*)(zbase + (size_t)l * NH);
            float dot = 0.f;
#pragma unroll
            for (int c = 0; c < 4; ++c) dot += dot4f(zr[c * 64 + lane], qk[c]);
#pragma unroll
            for (int s = 32; s; s >>= 1) dot += __shfl_down(dot, s, 64);
            if (lane == 0) logits[l] = dot * 0.03125f;   // 1/sqrt(1024)
        }
    }
    __syncthreads();

    // phase 2a: softmax over l (wave 0), fold retrieval weight
    if (t < 64) {
        float v = logits[t];
        float m = v;
#pragma unroll
        for (int s = 1; s < 64; s <<= 1) m = fmaxf(m, __shfl_xor(m, s, 64));
        float e = __expf(v - m);
        float sum = e;
#pragma unroll
        for (int s = 1; s < 64; s <<= 1) sum += __shfl_xor(sum, s, 64);
        coef[t] = weights[b * NK + k] * e / sum;
    }
    __syncthreads();

    // phase 2b: thread t owns output float4 column t; sum over 64 rows
    {
        float4 acc = make_float4(0.f, 0.f, 0.f, 0.f);
        for (int l = 0; l < NL; ++l) {
            float c = coef[l];
            float4 z = ((const float4*)(zbase + (size_t)l * NH))[t];
            acc.x += c * z.x; acc.y += c * z.y; acc.z += c * z.z; acc.w += c * z.w;
        }
        ((float4*)patt)[((size_t)b * NK + k) * 256 + t] = acc;
    }
}

// ---------------------------------------------------------------------------
// buildF: F[b][0:1024] = sum_k patt[b][k][:], F[b][1024:2048] = inputs[b]
// ---------------------------------------------------------------------------
__global__ __launch_bounds__(256)
void buildF_kernel(const float* __restrict__ patt,
                   const float* __restrict__ inputs,
                   float* __restrict__ F) {
    int gid = blockIdx.x * 256 + threadIdx.x;   // 0..16383 float4s
    int b = gid >> 9, j4 = gid & 511;
    float4 v;
    if (j4 < 256) {
        v = make_float4(0.f, 0.f, 0.f, 0.f);
#pragma unroll
        for (int k = 0; k < NK; ++k) {
            float4 p = ((const float4*)patt)[((size_t)b * NK + k) * 256 + j4];
            v.x += p.x; v.y += p.y; v.z += p.z; v.w += p.w;
        }
    } else {
        v = ((const float4*)(inputs + (size_t)b * NE))[j4 - 256];
    }
    ((float4*)F)[(size_t)b * 512 + j4] = v;
}

// ---------------------------------------------------------------------------
// FINAL: out = F @ Wc^T + bc
// ---------------------------------------------------------------------------
__global__ __launch_bounds__(256)
void final_kernel(const float* __restrict__ F,
                  const float* __restrict__ Wc,
                  const float* __restrict__ bc,
                  float* __restrict__ out) {
    int wid = blockIdx.x * 4 + (threadIdx.x >> 6);  // 0..4095
    rowdot8<2048>(F, Wc, bc, out, wid);
}

// ---------------------------------------------------------------------------
extern "C" void kernel_launch(void* const* d_in, const int* in_sizes, int n_in,
                              void* d_out, int out_size, void* d_ws, size_t ws_size,
                              hipStream_t stream) {
    const float* inputs       = (const float*)d_in[0];
    const float* Wq           = (const float*)d_in[1];
    const float* bq           = (const float*)d_in[2];
    const float* Wk           = (const float*)d_in[3];
    // d_in[4] = bk: cancels in the l-softmax (constant over l)
    const float* Wc           = (const float*)d_in[5];
    const float* bc           = (const float*)d_in[6];
    const float* cache_keys   = (const float*)d_in[7];
    const float* cache_values = (const float*)d_in[8];
    float* out = (float*)d_out;

    float* ws      = (float*)d_ws;
    float* scores  = ws;                       // 4096
    float* query   = scores + 4096;            // 32768
    float* pqk     = query + 32768;            // 8*32*1024 = 262144
    float* patt    = pqk + 262144;             // 32*8*1024 = 262144
    float* F       = patt + 262144;            // 65536
    float* weights = F + 65536;                // 256
    int*   tidx    = (int*)(weights + 256);    // 256 ints
    (void)ws_size; (void)n_in; (void)in_sizes; (void)out_size;

    fat1_kernel<<<2048, 256, 0, stream>>>(cache_keys, inputs, Wq, bq, scores, query);
    fat2_kernel<<<1056, 256, 0, stream>>>(query, Wk, scores, pqk, tidx, weights);
    attn_kernel<<<NB * NK, 256, 0, stream>>>(pqk, cache_values, tidx, weights, patt);
    buildF_kernel<<<64, 256, 0, stream>>>(patt, inputs, F);
    final_kernel<<<1024, 256, 0, stream>>>(F, Wc, bc, out);
}